// Round 4
// baseline (443.066 us; speedup 1.0000x reference)
//
#include <hip/hip_runtime.h>
#include <hip/hip_bf16.h>
#include <stdint.h>

// ---- problem constants ----
#define N_IMG 32
#define C_IN  256
#define HW    56
#define PIX   3136            // 56*56
#define M_TOT 100352          // 32*3136
#define C_OUT 256
#define K_TOT 2304            // 256*9
#define HP    58
#define WPAD  58
#define OUT_IMG_STRIDE 802816 // 256*3136

// ---- tile config: BM=128 px (per-image tiles), BN=128, 512-thr blocks ----
#define BM 128
#define BN 128
#define SLAB_PX 348           // 6 padded rows * 58 cols
#define NSLOT 1392            // SLAB_PX * 4 (16B parts)

typedef __attribute__((ext_vector_type(8))) short bf16x8_t;   // 8 bf16 = 4 VGPRs
typedef __attribute__((ext_vector_type(4))) float f32x4_t;

// ---------------- pass 0: zero only the padded border -------------------------------
__global__ void border_zero_kernel(__hip_bfloat16* __restrict__ xpad) {
    int t = blockIdx.x * 256 + threadIdx.x;   // 32 n * 228 border px * 32 uint4
    if (t >= 32 * 228 * 32) return;
    int n = t / (228 * 32);
    int r = t - n * (228 * 32);
    int px = r >> 5, part = r & 31;
    int hp, wp;
    if (px < 58)       { hp = 0;  wp = px; }
    else if (px < 116) { hp = 57; wp = px - 116 + 58; }
    else { int k = px - 116; hp = 1 + (k >> 1); wp = (k & 1) ? 57 : 0; }
    long e = (((long)n * HP + hp) * WPAD + wp) * C_IN + part * 8;
    *(uint4*)(xpad + e) = make_uint4(0u, 0u, 0u, 0u);
}

// ---------------- pass 1: NCHW fp32 -> padded NHWC bf16 transpose --------------------
__global__ void xform_kernel(const float* __restrict__ x, __hip_bfloat16* __restrict__ xpad) {
    __shared__ float tile[64][65];
    int b   = blockIdx.x;
    int n   = b / 196;
    int rem = b - n * 196;
    int ct  = rem / 49;
    int pt  = rem - ct * 49;
    int c0 = ct * 64, p0 = pt * 64;
    int t = threadIdx.x;

    const float* xs = x + (size_t)n * C_IN * PIX;
    int pc = t & 63, cr = t >> 6;   // read: coalesced along pixels
#pragma unroll
    for (int it = 0; it < 16; ++it) {
        int c = c0 + it * 4 + cr;
        tile[it * 4 + cr][pc] = xs[(size_t)c * PIX + p0 + pc];
    }
    __syncthreads();
    // write: 4 chans/lane, ushort4 (8 B) stores
    int l = t & 63, wv = t >> 6;
    int mq = l & 15, pxw = l >> 4;
#pragma unroll
    for (int it = 0; it < 4; ++it) {
        int px = it * 16 + wv * 4 + pxw;    // 0..63
        int gp = p0 + px;
        int h = gp / 56, w = gp - h * 56;
        float f0 = tile[4 * mq + 0][px];
        float f1 = tile[4 * mq + 1][px];
        float f2 = tile[4 * mq + 2][px];
        float f3 = tile[4 * mq + 3][px];
        __hip_bfloat16 b0 = __float2bfloat16(f0), b1 = __float2bfloat16(f1);
        __hip_bfloat16 b2 = __float2bfloat16(f2), b3 = __float2bfloat16(f3);
        ushort4 v;
        v.x = *(unsigned short*)&b0; v.y = *(unsigned short*)&b1;
        v.z = *(unsigned short*)&b2; v.w = *(unsigned short*)&b3;
        *(ushort4*)&xpad[(((size_t)n * HP + h + 1) * WPAD + (w + 1)) * C_IN + c0 + 4 * mq] = v;
    }
}

// ---------------- pass 2: binarize + transpose weights -> wt[cout][tap][c] bf16 -------
__global__ void wxform_kernel(const float* __restrict__ w, __hip_bfloat16* __restrict__ wt) {
    int i = blockIdx.x * 256 + threadIdx.x;   // over 589824
    if (i >= C_OUT * K_TOT) return;
    int cout = i / K_TOT;
    int r    = i - cout * K_TOT;
    int tap  = r >> 8;
    int c    = r & 255;
    float v = w[cout * 2304 + c * 9 + tap];   // [cout][cin][3][3]
    float s = (v > 0.f) ? 1.f : ((v < 0.f) ? -1.f : 0.f);
    wt[i] = __float2bfloat16(s);
}

// ---------------- pass 3: slab-reuse implicit-GEMM conv ------------------------------
// 512 threads = 8 waves (2m x 4n); wave = 64m x 32n -> acc 4x2 f32x4 = 32 regs.
// Per 32-chan chunk: VGPR-pipelined slab staging (loads for ch+1 issued before
// compute of ch), 9 taps x 8 MFMA from a swizzled packed slab; B direct from
// global (L2-hot). Register-light => 4 waves/SIMD (16 waves/CU).
__global__ void __launch_bounds__(512, 4)
gemm_kernel(const __hip_bfloat16* __restrict__ xpad,
            const __hip_bfloat16* __restrict__ wt,
            const float* __restrict__ bias,
            float* __restrict__ out) {
    // packed slab: pixel pp at byte pp*64; 16B part-slot q holds chan-part
    // p = (q - (pp>>1)) & 3  (XOR-ish swizzle, verified R3: conflicts 9.5M->1M)
    __shared__ __hip_bfloat16 slab[SLAB_PX * 32];   // 22272 B

    int bx = blockIdx.x;                 // 1600 blocks; bx, bx+8 share an XCD
    int g = bx >> 4, xg = bx & 7, nt = (bx >> 3) & 1;
    int mt = g * 8 + xg;                 // 0..799
    int nimg = mt / 25, kk = mt - nimg * 25;
    int p0 = kk * BM;                    // first pixel (per-image, tail masked)
    int r0 = p0 / 56; if (r0 > 52) r0 = 52;
    int n0 = nt * BN;

    int tid = threadIdx.x, lane = tid & 63, wv = tid >> 6;
    int wm = wv >> 2, wn = wv & 3;
    int ar = lane & 15, kq = lane >> 4;

    const __hip_bfloat16* winBase = xpad + ((long)(nimg * HP + r0) * WPAD) * C_IN;

    // staging slots: s -> pp = s>>2, part-slot q = s&3 stores chan-part (q-(pp>>1))&3
    int s0 = tid, s1 = tid + 512, s2 = tid + 1024;
    bool act2 = (s2 < NSLOT);
    int pA = s0 >> 2, pB = s1 >> 2, pC = s2 >> 2;
    int soA = pA * 256 + (((s0 & 3) - (pA >> 1)) & 3) * 8;
    int soB = pB * 256 + (((s1 & 3) - (pB >> 1)) & 3) * 8;
    int soC = pC * 256 + (((s2 & 3) - (pC >> 1)) & 3) * 8;

    // a-frag pixel index (tap 0,0): local m = wm*64 + i*16 + ar
    int pp0[4];
#pragma unroll
    for (int i = 0; i < 4; ++i) {
        int p = p0 + wm * 64 + i * 16 + ar;
        if (p > PIX - 1) p = PIX - 1;          // tail clamp (results masked)
        int rg = p / 56, c = p - rg * 56;
        pp0[i] = (rg - r0) * 58 + c;
    }
    const int TAP_PP[9] = {0, 1, 2, 58, 59, 60, 116, 117, 118};

    // B element offsets
    int wb[2];
#pragma unroll
    for (int j = 0; j < 2; ++j)
        wb[j] = (n0 + wn * 32 + j * 16 + ar) * K_TOT + kq * 8;

    f32x4_t acc[4][2] = {};

    // prologue: stage chunk 0
    {
        uint4 vA = *(const uint4*)(winBase + soA);
        uint4 vB = *(const uint4*)(winBase + soB);
        uint4 vC;
        if (act2) vC = *(const uint4*)(winBase + soC);
        *(uint4*)((char*)slab + s0 * 16) = vA;
        *(uint4*)((char*)slab + s1 * 16) = vB;
        if (act2) *(uint4*)((char*)slab + s2 * 16) = vC;
    }
    __syncthreads();

    for (int ch = 0; ch < 8; ++ch) {
        int cho = ch * 32;
        // prefetch next chunk into VGPRs; latency hidden under the tap loop
        uint4 nA, nB, nC;
        if (ch < 7) {
            nA = *(const uint4*)(winBase + soA + cho + 32);
            nB = *(const uint4*)(winBase + soB + cho + 32);
            if (act2) nC = *(const uint4*)(winBase + soC + cho + 32);
        }
#pragma unroll
        for (int t = 0; t < 9; ++t) {
            bf16x8_t b[2];
#pragma unroll
            for (int j = 0; j < 2; ++j)
                b[j] = *(const bf16x8_t*)(wt + wb[j] + t * 256 + cho);
            bf16x8_t a[4];
#pragma unroll
            for (int i = 0; i < 4; ++i) {
                int pp = pp0[i] + TAP_PP[t];
                int off = pp * 64 + (((kq + (pp >> 1)) & 3) << 4);
                a[i] = *(const bf16x8_t*)((const char*)slab + off);
            }
#pragma unroll
            for (int i = 0; i < 4; ++i)
#pragma unroll
                for (int j = 0; j < 2; ++j)
                    acc[i][j] = __builtin_amdgcn_mfma_f32_16x16x32_bf16(a[i], b[j], acc[i][j], 0, 0, 0);
        }
        if (ch < 7) {
            __syncthreads();                     // all waves done reading slab
            *(uint4*)((char*)slab + s0 * 16) = nA;
            *(uint4*)((char*)slab + s1 * 16) = nB;
            if (act2) *(uint4*)((char*)slab + s2 * 16) = nC;
            __syncthreads();                     // stores visible
        }
    }

    // epilogue: C/D col=lane&15 (n), row=(lane>>4)*4+reg (m); float4 stores along m
    int cn = lane & 15;
    int rq = (lane >> 4) * 4;
    long outb = (long)nimg * OUT_IMG_STRIDE;
#pragma unroll
    for (int i = 0; i < 4; ++i) {
        int pix = p0 + wm * 64 + i * 16 + rq;
        if (pix < PIX) {                         // tail mask (4-aligned vs 3136)
#pragma unroll
            for (int j = 0; j < 2; ++j) {
                int cout = n0 + wn * 32 + j * 16 + cn;
                float bv = bias[cout];
                f32x4_t v = acc[i][j];
                v[0] += bv; v[1] += bv; v[2] += bv; v[3] += bv;
                *(f32x4_t*)&out[outb + (long)cout * PIX + pix] = v;
            }
        }
    }
}

extern "C" void kernel_launch(void* const* d_in, const int* in_sizes, int n_in,
                              void* d_out, int out_size, void* d_ws, size_t ws_size,
                              hipStream_t stream) {
    const float* x    = (const float*)d_in[0];
    const float* wgt  = (const float*)d_in[1];
    const float* bias = (const float*)d_in[2];
    float* out = (float*)d_out;

    __hip_bfloat16* xpad = (__hip_bfloat16*)d_ws;                       // 55,115,776 B
    __hip_bfloat16* wt   = (__hip_bfloat16*)((char*)d_ws + 55115776);   // 1,179,648 B

    border_zero_kernel<<<dim3((32 * 228 * 32 + 255) / 256), dim3(256), 0, stream>>>(xpad);
    xform_kernel<<<dim3(N_IMG * 4 * 49), dim3(256), 0, stream>>>(x, xpad);
    wxform_kernel<<<dim3((C_OUT * K_TOT + 255) / 256), dim3(256), 0, stream>>>(wgt, wt);
    // 32 images * 25 m-tiles * 2 n-tiles = 1600 blocks of 512 threads
    gemm_kernel<<<dim3(1600), dim3(512), 0, stream>>>(xpad, wt, bias, out);
}